// Round 1
// baseline (533.299 us; speedup 1.0000x reference)
//
#include <hip/hip_runtime.h>
#include <hip/hip_fp16.h>

// ---- R6 CSR-build constants (verbatim; load-bearing for agg locality) ----
#define NBLK_BIN 256   // bin blocks; chunking identical to r3/r5/r6 -> same per-cell counts
#define NBKT 196       // ceil(100000/512) dst-buckets
#define BWIN 512       // nodes per bucket
#define CAP 128        // slots per (block,bucket); lambda=63.8, +8 sigma -> no overflow

// NOTE (R8/R9 post-mortem): R6's exact CSR build (NBLK=256, CAP=128, monotone
// bucket bases, this fill structure) is empirically tied to the width-64 agg
// running at 67us/158MB FETCH. R7-style atomic-span fill or finer bin chunking
// pushed agg FETCH to 298MB (+24us). Feature-slicing (R9) regressed net.
// Keep CSR output structure EXACT; only change execution parallelism.
//
// R10 theory: aggs are latency-bound random gathers pinned at the per-CU
// miss-concurrency cap -> time ~ avg miss latency. Gather L2 hit rate is only
// ~33% (FETCH decomp: 133MB gather misses / 410MB gather lines) because each
// pass streams ~25MB of zero-reuse traffic (srcs reads, output write-allocate,
// gemm dead-input reads) through the same per-XCD L2s. Fix: non-temporal hints
// on ALL streaming accesses; keep gather loads + gemm outputs (next gather
// target) cached. Correct polarity of R7's failed NT (R7 NT'd the gathers).

typedef unsigned int uint;

union U32H2 { uint u; __half2 h; };

__device__ inline float2 h2_to_f2(uint u) {
    U32H2 c; c.u = u;
    return __half22float2(c.h);
}
__device__ inline uint f2_to_h2(float a, float b) {
    U32H2 c; c.h = __floats2half2_rn(a, b);
    return c.u;
}

// ---------------- CSR build: bin pass (R6 verbatim: 1024 thr, no global atomics) ----------------
__global__ __launch_bounds__(1024) void bin_kernel(const int* __restrict__ src,
                                                   const int* __restrict__ dst,
                                                   int2* __restrict__ pairs,
                                                   int* __restrict__ blkcnt, int e) {
    __shared__ int lcnt[NBKT];
    int blk = blockIdx.x, tid = threadIdx.x;
    for (int t = tid; t < NBKT; t += 1024) lcnt[t] = 0;
    __syncthreads();
    int chunk = (e + NBLK_BIN - 1) / NBLK_BIN;
    int base = blk * chunk;
    int end = min(e, base + chunk);
    for (int i = base + tid; i < end; i += 1024) {
        int s = src[i], d = dst[i];
        int b = d >> 9;
        int pos = atomicAdd(&lcnt[b], 1);
        if (pos < CAP) pairs[((size_t)blk * NBKT + b) * CAP + pos] = make_int2(s, d);
    }
    __syncthreads();
    for (int t = tid; t < NBKT; t += 1024) blkcnt[blk * NBKT + t] = min(lcnt[t], CAP);
}

// ---------------- fused fill: in-block bucket base + counts + scan + cnt/rowptr/dinv + srcs ----
// 1024 threads (was 512): fill was 13%-occupancy latency-bound at 50us (R9 PMC).
// Bucket base computed in-block (= R6 bucket_scan value exactly, deterministic sum).
__global__ __launch_bounds__(1024) void fill_kernel(const int2* __restrict__ pairs,
                                                    const int* __restrict__ blkcnt,
                                                    int* __restrict__ srcs,
                                                    int* __restrict__ cnt,
                                                    int* __restrict__ rowptr,
                                                    float* __restrict__ dinv, int n) {
    __shared__ int lc[BWIN];
    __shared__ int ps[BWIN];
    __shared__ int sm[NBLK_BIN];
    __shared__ int gbase_s;
    int b = blockIdx.x, tid = threadIdx.x;
    int nbase = b << 9;
    if (tid < BWIN) lc[tid] = 0;
    for (int t = tid; t < NBLK_BIN; t += 1024) sm[t] = blkcnt[t * NBKT + b];
    if (tid == 0) gbase_s = 0;
    __syncthreads();
    // bucket base: sum over all bin-blocks of all buckets b' < b (L2-hot 200KB array)
    {
        long long tot = (long long)NBLK_BIN * b;
        int lsum = 0;
        for (long long j = tid; j < tot; j += 1024) {
            int blk = (int)(j / b);
            int bp  = (int)(j - (long long)blk * b);
            lsum += blkcnt[blk * NBKT + bp];
        }
        for (int o = 32; o > 0; o >>= 1) lsum += __shfl_down(lsum, o, 64);
        if ((tid & 63) == 0 && lsum != 0) atomicAdd(&gbase_s, lsum);
    }
    int wave = tid >> 6, lane = tid & 63;
    // pass 1: per-node counts (16 waves over 256 cells)
    for (int blk = wave; blk < NBLK_BIN; blk += 16) {
        int m = sm[blk];
        const int2* p = pairs + ((size_t)blk * NBKT + b) * CAP;
        for (int i = lane; i < m; i += 64) atomicAdd(&lc[p[i].y - nbase], 1);
    }
    __syncthreads();
    // exclusive scan of 512 counts (first 512 threads active; all hit barriers)
    int myc = (tid < BWIN) ? lc[tid] : 0;
    if (tid < BWIN) ps[tid] = myc;
    __syncthreads();
    for (int off = 1; off < BWIN; off <<= 1) {
        int t = 0;
        if (tid < BWIN && tid >= off) t = ps[tid - off];
        __syncthreads();
        if (tid < BWIN) ps[tid] += t;
        __syncthreads();
    }
    int gbase = gbase_s;
    if (tid < BWIN) {
        int ex = ps[tid] - myc;
        int vtx = nbase + tid;
        if (vtx < n) {
            cnt[vtx] = myc;
            rowptr[vtx] = gbase + ex;
            dinv[vtx] = rsqrtf(1.0f + (float)myc);   // +1: self-loop
        }
    }
    __syncthreads();
    if (tid < BWIN) lc[tid] = ps[tid] - myc;   // reuse as bucket-relative cursor
    __syncthreads();
    // pass 2: place srcs (contiguous monotone span for this bucket)
    for (int blk = wave; blk < NBLK_BIN; blk += 16) {
        int m = sm[blk];
        const int2* p = pairs + ((size_t)blk * NBKT + b) * CAP;
        for (int i = lane; i < m; i += 64) {
            int2 e2 = p[i];
            int o = atomicAdd(&lc[e2.y - nbase], 1);
            srcs[gbase + o] = e2.x;
        }
    }
}

// ---------------- input feature build: half, stride 4 uints, pre-scaled by dinv ----------------

__global__ __launch_bounds__(256) void build_x0_h_kernel(const float* __restrict__ coords,
                                                         const int* __restrict__ at,
                                                         const float* __restrict__ emb,
                                                         const float* __restrict__ dinv,
                                                         uint* __restrict__ x, int n) {
    int v = blockIdx.x * 256 + threadIdx.x;
    if (v >= n) return;
    float dv = dinv[v];
    float c0 = coords[3 * v + 0] * dv;
    float c1 = coords[3 * v + 1] * dv;
    float c2 = coords[3 * v + 2] * dv;
    int t = at[v];
    float e0 = emb[3 * t + 0] * dv;
    float e1 = emb[3 * t + 1] * dv;
    float e2 = emb[3 * t + 2] * dv;
    uint* row = x + (size_t)v * 4;
    row[0] = f2_to_h2(c0, c1);   // x0 is L1's gather target: keep cached (default)
    row[1] = f2_to_h2(c2, e0);
    row[2] = f2_to_h2(e1, e2);
    row[3] = 0;
}

// ---------------- packed-half aggregation (R6 structure; R10: NT on streams only) ----------------
// unroll-4 plain GATHER loads = measured sweet spot (67us/158MB); NT must NEVER
// touch the gather loads (R7 regression). srcs reads + out stores are zero-reuse
// streams -> non-temporal so they stop evicting the gather set from per-XCD L2.
template <int FPH2, bool HAS_BIAS, bool RELU>
__global__ __launch_bounds__(256) void agg_h_kernel(const uint* __restrict__ in,
                                                    const float* __restrict__ dinv,
                                                    const int* __restrict__ rowptr,
                                                    const int* __restrict__ cnt,
                                                    const int* __restrict__ srcs,
                                                    const float* __restrict__ bias,
                                                    uint* __restrict__ out, int n) {
    int gid = blockIdx.x * 256 + threadIdx.x;
    int v = gid / FPH2, j2 = gid % FPH2;
    if (v >= n) return;
    float2 s0 = h2_to_f2(in[(size_t)v * FPH2 + j2]);
    float accx = s0.x, accy = s0.y;
    int start = rowptr[v];
    int len = cnt[v];
    int k = 0;
    for (; k + 4 <= len; k += 4) {
        int sA = __builtin_nontemporal_load(srcs + start + k);
        int sB = __builtin_nontemporal_load(srcs + start + k + 1);
        int sC = __builtin_nontemporal_load(srcs + start + k + 2);
        int sD = __builtin_nontemporal_load(srcs + start + k + 3);
        float2 fA = h2_to_f2(in[(size_t)sA * FPH2 + j2]);
        float2 fB = h2_to_f2(in[(size_t)sB * FPH2 + j2]);
        float2 fC = h2_to_f2(in[(size_t)sC * FPH2 + j2]);
        float2 fD = h2_to_f2(in[(size_t)sD * FPH2 + j2]);
        accx += (fA.x + fB.x) + (fC.x + fD.x);
        accy += (fA.y + fB.y) + (fC.y + fD.y);
    }
    for (; k < len; ++k) {
        int s = __builtin_nontemporal_load(srcs + start + k);
        float2 f = h2_to_f2(in[(size_t)s * FPH2 + j2]);
        accx += f.x; accy += f.y;
    }
    float dv = dinv[v];
    accx *= dv; accy *= dv;
    if (HAS_BIAS) { accx += bias[2 * j2]; accy += bias[2 * j2 + 1]; }
    if (RELU) { accx = fmaxf(accx, 0.0f); accy = fmaxf(accy, 0.0f); }
    __builtin_nontemporal_store(f2_to_h2(accx, accy), out + (size_t)v * FPH2 + j2);
}

// ---------------- half GEMM: fp32 accumulate, packed-half (or fp32) out ----------------
// R10: input rows are read-once dead data (agg output) -> NT load. Output rows
// are the NEXT agg's gather target -> default (cached) store.
template <int DIN, int DOUT, int DOUTH2, bool HAS_BIAS, bool RELU, bool SCALE, bool OUTF>
__global__ __launch_bounds__(256) void gemm_h_kernel(const uint* __restrict__ xin,
                                                     const float* __restrict__ W,
                                                     const float* __restrict__ bias,
                                                     const float* __restrict__ dinv,
                                                     void* __restrict__ xout,
                                                     int istride_u, int ostride, int n) {
    __shared__ float wlds[DIN * DOUT];
    for (int i = threadIdx.x; i < DIN * DOUT; i += 256) wlds[i] = W[i];
    __syncthreads();
    int gid = blockIdx.x * 256 + threadIdx.x;
    int v = gid / DOUTH2, j2 = gid % DOUTH2;
    if (v >= n) return;
    int j1 = 2 * j2;
    const uint* xr = xin + (size_t)v * istride_u;
    float acc0 = 0.0f, acc1 = 0.0f;
#pragma unroll
    for (int ku = 0; ku < DIN / 2; ++ku) {
        float2 xf = h2_to_f2(__builtin_nontemporal_load(xr + ku));
        int k = 2 * ku;
        acc0 = fmaf(xf.x, wlds[k * DOUT + j1], acc0);
        acc0 = fmaf(xf.y, wlds[(k + 1) * DOUT + j1], acc0);
        if (j1 + 1 < DOUT) {
            acc1 = fmaf(xf.x, wlds[k * DOUT + j1 + 1], acc1);
            acc1 = fmaf(xf.y, wlds[(k + 1) * DOUT + j1 + 1], acc1);
        }
    }
    if (HAS_BIAS) {
        acc0 += bias[j1];
        if (j1 + 1 < DOUT) acc1 += bias[j1 + 1];
    }
    if (RELU) { acc0 = fmaxf(acc0, 0.0f); acc1 = fmaxf(acc1, 0.0f); }
    if (SCALE) { float dv = dinv[v]; acc0 *= dv; acc1 *= dv; }
    if (OUTF) {
        float* o = (float*)xout + (size_t)v * ostride;
        o[j1] = acc0;
        if (j1 + 1 < DOUT) o[j1 + 1] = acc1;
    } else {
        ((uint*)xout)[(size_t)v * ostride + j2] = f2_to_h2(acc0, acc1);
    }
}

// ---------------- fp32 final aggregation (L5; R10: NT on streams) ----------------
template <int F, int FP, bool HAS_BIAS, bool RELU>
__global__ __launch_bounds__(256) void agg_f_kernel(const float* __restrict__ in,
                                                    const float* __restrict__ dinv,
                                                    const int* __restrict__ rowptr,
                                                    const int* __restrict__ cnt,
                                                    const int* __restrict__ srcs,
                                                    const float* __restrict__ b,
                                                    float* __restrict__ out,
                                                    int istride, int ostride, int n) {
    int gid = blockIdx.x * 256 + threadIdx.x;
    int v = gid / FP, j = gid % FP;
    if (v >= n || j >= F) return;
    float dv = dinv[v];
    int start = rowptr[v];
    int len = cnt[v];
    float acc = in[(size_t)v * istride + j];
    int k = 0;
    for (; k + 4 <= len; k += 4) {
        int s0 = __builtin_nontemporal_load(srcs + start + k);
        int s1 = __builtin_nontemporal_load(srcs + start + k + 1);
        int s2 = __builtin_nontemporal_load(srcs + start + k + 2);
        int s3 = __builtin_nontemporal_load(srcs + start + k + 3);
        float a0 = in[(size_t)s0 * istride + j];
        float a1 = in[(size_t)s1 * istride + j];
        float a2 = in[(size_t)s2 * istride + j];
        float a3 = in[(size_t)s3 * istride + j];
        acc += (a0 + a1) + (a2 + a3);
    }
    for (; k < len; ++k) acc += in[(size_t)__builtin_nontemporal_load(srcs + start + k) * istride + j];
    float val = acc * dv;
    if (HAS_BIAS) val += b[j];
    if (RELU) val = fmaxf(val, 0.0f);
    __builtin_nontemporal_store(val, out + (size_t)v * ostride + j);
}

// ---------------- driver ----------------

extern "C" void kernel_launch(void* const* d_in, const int* in_sizes, int n_in,
                              void* d_out, int out_size, void* d_ws, size_t ws_size,
                              hipStream_t stream) {
    const float* coords = (const float*)d_in[0];
    const int* at       = (const int*)d_in[1];
    const int* ei       = (const int*)d_in[2];
    const float* emb    = (const float*)d_in[3];
    const float* W1 = (const float*)d_in[4];  const float* b1 = (const float*)d_in[5];
    const float* W2 = (const float*)d_in[6];  const float* b2 = (const float*)d_in[7];
    const float* W3 = (const float*)d_in[8];  const float* b3 = (const float*)d_in[9];
    const float* W4 = (const float*)d_in[10]; const float* b4 = (const float*)d_in[11];
    const float* W5 = (const float*)d_in[12]; const float* b5 = (const float*)d_in[13];
    float* out = (float*)d_out;

    const int n = in_sizes[0] / 3;   // 100000
    const int e = in_sizes[2] / 2;   // 3200000
    const int* src = ei;
    const int* dst = ei + e;

    // workspace layout (pairs dies before feature buffers are born -> alias)
    char* ws = (char*)d_ws;
    size_t off = 0;
    float* dinv   = (float*)(ws + off); off += (size_t)n * 4;
    int*   cnt    = (int*)(ws + off);   off += (size_t)n * 4;
    int*   rowptr = (int*)(ws + off);   off += (size_t)n * 4;
    int*   blkcnt = (int*)(ws + off);   off += (size_t)NBLK_BIN * NBKT * 4;
    int*   srcs   = (int*)(ws + off);   off += (size_t)e * 4;
    char*  alias  = ws + off;           // max(pairs 51.4MB, A_h+B_h+B_f 27.2MB)
    int2*  pairs  = (int2*)alias;
    uint*  A_h    = (uint*)alias;                    // n x 32 uints
    uint*  B_h    = A_h + (size_t)n * 32;            // n x 32 uints
    float* B_f    = (float*)(B_h + (size_t)n * 32);  // n x 4 floats

    int nb = (n + 255) / 256;   // 391

    // ---- CSR build (R6 output structure; fill 1024-thr with in-block base) ----
    bin_kernel<<<NBLK_BIN, 1024, 0, stream>>>(src, dst, pairs, blkcnt, e);
    fill_kernel<<<NBKT, 1024, 0, stream>>>(pairs, blkcnt, srcs, cnt, rowptr, dinv, n);

    // ---- x0 (pre-scaled by dinv), half stride 4 uints, in A_h ----
    build_x0_h_kernel<<<nb, 256, 0, stream>>>(coords, at, emb, dinv, A_h, n);

    auto blocks = [](long long threads) { return (int)((threads + 255) / 256); };

    // L1: 6->32. agg width6(FPH2=4); gemm + bias + relu + dinv-prescale
    agg_h_kernel<4, false, false><<<blocks((long long)n * 4), 256, 0, stream>>>(
        A_h, dinv, rowptr, cnt, srcs, nullptr, B_h, n);
    gemm_h_kernel<6, 32, 16, true, true, true, false><<<blocks((long long)n * 16), 256, 0, stream>>>(
        B_h, W1, b1, dinv, A_h, 4, 16, n);

    // L2: 32->64. agg width32(FPH2=16); gemm + bias + relu + dinv-prescale
    agg_h_kernel<16, false, false><<<blocks((long long)n * 16), 256, 0, stream>>>(
        A_h, dinv, rowptr, cnt, srcs, nullptr, B_h, n);
    gemm_h_kernel<32, 64, 32, true, true, true, false><<<blocks((long long)n * 32), 256, 0, stream>>>(
        B_h, W2, b2, dinv, A_h, 16, 32, n);

    // L3: 64->64. agg width64(FPH2=32); gemm + bias + relu (no scale: L4 is post-agg)
    agg_h_kernel<32, false, false><<<blocks((long long)n * 32), 256, 0, stream>>>(
        A_h, dinv, rowptr, cnt, srcs, nullptr, B_h, n);
    gemm_h_kernel<64, 64, 32, true, true, false, false><<<blocks((long long)n * 32), 256, 0, stream>>>(
        B_h, W3, b3, dinv, A_h, 32, 32, n);

    // L4: 64->32 post-agg. gemm scale-only -> B_h; agg width32 + bias + relu -> A_h
    gemm_h_kernel<64, 32, 16, false, false, true, false><<<blocks((long long)n * 16), 256, 0, stream>>>(
        A_h, W4, nullptr, dinv, B_h, 32, 16, n);
    agg_h_kernel<16, true, true><<<blocks((long long)n * 16), 256, 0, stream>>>(
        B_h, dinv, rowptr, cnt, srcs, b4, A_h, n);

    // L5: 32->3 post-agg, fp32 path. gemm scale-only -> B_f; agg + bias -> out
    gemm_h_kernel<32, 3, 2, false, false, true, true><<<blocks((long long)n * 2), 256, 0, stream>>>(
        A_h, W5, nullptr, dinv, B_f, 16, 4, n);
    agg_f_kernel<3, 4, true, false><<<blocks((long long)n * 4), 256, 0, stream>>>(
        B_f, dinv, rowptr, cnt, srcs, b5, out, 4, 3, n);
}

// Round 2
// 430.660 us; speedup vs baseline: 1.2383x; 1.2383x over previous
//
#include <hip/hip_runtime.h>
#include <hip/hip_fp16.h>

// ---- R6 CSR-build constants (verbatim; load-bearing for agg locality) ----
#define NBLK_BIN 256   // bin blocks; chunking identical to r3/r5/r6 -> same per-cell counts
#define NBKT 196       // ceil(100000/512) dst-buckets
#define BWIN 512       // nodes per bucket
#define CAP 128        // slots per (block,bucket); lambda=63.8, +8 sigma -> no overflow

// NOTE (R8/R9 post-mortem): R6's exact CSR build (NBLK=256, CAP=128, monotone
// bucket bases, this fill structure) is empirically tied to the width-64 agg
// running at 67us/158MB FETCH. R7-style atomic-span fill or finer bin chunking
// pushed agg FETCH to 298MB (+24us). Feature-slicing (R9) regressed net.
// Keep CSR output structure EXACT; only change execution parallelism.
//
// NOTE (R10 post-mortem): __builtin_nontemporal on srcs reads / gemm input rows
// REGRESSED +80us. Those accesses have heavy L1 reuse (32 threads lockstep on
// the same srcs line; 16 ku-iterations per input line). NT anywhere in this
// kernel family loses. Do not reintroduce.
//
// R11: aggs + CSR byte-identical to the 452us baseline. Wins taken from dense
// glue only: (a) L3gemm+L4gemm fused (h kept fp32 in LDS, A_h 64-wide round
// trip eliminated), (b) L5 gemm folded into L4 agg epilogue via width-16
// shfl_xor reduce (32-wide L4 output never materialized).

typedef unsigned int uint;

union U32H2 { uint u; __half2 h; };

__device__ inline float2 h2_to_f2(uint u) {
    U32H2 c; c.u = u;
    return __half22float2(c.h);
}
__device__ inline uint f2_to_h2(float a, float b) {
    U32H2 c; c.h = __floats2half2_rn(a, b);
    return c.u;
}

// ---------------- CSR build: bin pass (R6 verbatim: 1024 thr, no global atomics) ----------------
__global__ __launch_bounds__(1024) void bin_kernel(const int* __restrict__ src,
                                                   const int* __restrict__ dst,
                                                   int2* __restrict__ pairs,
                                                   int* __restrict__ blkcnt, int e) {
    __shared__ int lcnt[NBKT];
    int blk = blockIdx.x, tid = threadIdx.x;
    for (int t = tid; t < NBKT; t += 1024) lcnt[t] = 0;
    __syncthreads();
    int chunk = (e + NBLK_BIN - 1) / NBLK_BIN;
    int base = blk * chunk;
    int end = min(e, base + chunk);
    for (int i = base + tid; i < end; i += 1024) {
        int s = src[i], d = dst[i];
        int b = d >> 9;
        int pos = atomicAdd(&lcnt[b], 1);
        if (pos < CAP) pairs[((size_t)blk * NBKT + b) * CAP + pos] = make_int2(s, d);
    }
    __syncthreads();
    for (int t = tid; t < NBKT; t += 1024) blkcnt[blk * NBKT + t] = min(lcnt[t], CAP);
}

// ---------------- fused fill: in-block bucket base + counts + scan + cnt/rowptr/dinv + srcs ----
// 1024 threads (was 512): fill was 13%-occupancy latency-bound at 50us (R9 PMC).
// Bucket base computed in-block (= R6 bucket_scan value exactly, deterministic sum).
__global__ __launch_bounds__(1024) void fill_kernel(const int2* __restrict__ pairs,
                                                    const int* __restrict__ blkcnt,
                                                    int* __restrict__ srcs,
                                                    int* __restrict__ cnt,
                                                    int* __restrict__ rowptr,
                                                    float* __restrict__ dinv, int n) {
    __shared__ int lc[BWIN];
    __shared__ int ps[BWIN];
    __shared__ int sm[NBLK_BIN];
    __shared__ int gbase_s;
    int b = blockIdx.x, tid = threadIdx.x;
    int nbase = b << 9;
    if (tid < BWIN) lc[tid] = 0;
    for (int t = tid; t < NBLK_BIN; t += 1024) sm[t] = blkcnt[t * NBKT + b];
    if (tid == 0) gbase_s = 0;
    __syncthreads();
    // bucket base: sum over all bin-blocks of all buckets b' < b (L2-hot 200KB array)
    {
        long long tot = (long long)NBLK_BIN * b;
        int lsum = 0;
        for (long long j = tid; j < tot; j += 1024) {
            int blk = (int)(j / b);
            int bp  = (int)(j - (long long)blk * b);
            lsum += blkcnt[blk * NBKT + bp];
        }
        for (int o = 32; o > 0; o >>= 1) lsum += __shfl_down(lsum, o, 64);
        if ((tid & 63) == 0 && lsum != 0) atomicAdd(&gbase_s, lsum);
    }
    int wave = tid >> 6, lane = tid & 63;
    // pass 1: per-node counts (16 waves over 256 cells)
    for (int blk = wave; blk < NBLK_BIN; blk += 16) {
        int m = sm[blk];
        const int2* p = pairs + ((size_t)blk * NBKT + b) * CAP;
        for (int i = lane; i < m; i += 64) atomicAdd(&lc[p[i].y - nbase], 1);
    }
    __syncthreads();
    // exclusive scan of 512 counts (first 512 threads active; all hit barriers)
    int myc = (tid < BWIN) ? lc[tid] : 0;
    if (tid < BWIN) ps[tid] = myc;
    __syncthreads();
    for (int off = 1; off < BWIN; off <<= 1) {
        int t = 0;
        if (tid < BWIN && tid >= off) t = ps[tid - off];
        __syncthreads();
        if (tid < BWIN) ps[tid] += t;
        __syncthreads();
    }
    int gbase = gbase_s;
    if (tid < BWIN) {
        int ex = ps[tid] - myc;
        int vtx = nbase + tid;
        if (vtx < n) {
            cnt[vtx] = myc;
            rowptr[vtx] = gbase + ex;
            dinv[vtx] = rsqrtf(1.0f + (float)myc);   // +1: self-loop
        }
    }
    __syncthreads();
    if (tid < BWIN) lc[tid] = ps[tid] - myc;   // reuse as bucket-relative cursor
    __syncthreads();
    // pass 2: place srcs (contiguous monotone span for this bucket)
    for (int blk = wave; blk < NBLK_BIN; blk += 16) {
        int m = sm[blk];
        const int2* p = pairs + ((size_t)blk * NBKT + b) * CAP;
        for (int i = lane; i < m; i += 64) {
            int2 e2 = p[i];
            int o = atomicAdd(&lc[e2.y - nbase], 1);
            srcs[gbase + o] = e2.x;
        }
    }
}

// ---------------- input feature build: half, stride 4 uints, pre-scaled by dinv ----------------

__global__ __launch_bounds__(256) void build_x0_h_kernel(const float* __restrict__ coords,
                                                         const int* __restrict__ at,
                                                         const float* __restrict__ emb,
                                                         const float* __restrict__ dinv,
                                                         uint* __restrict__ x, int n) {
    int v = blockIdx.x * 256 + threadIdx.x;
    if (v >= n) return;
    float dv = dinv[v];
    float c0 = coords[3 * v + 0] * dv;
    float c1 = coords[3 * v + 1] * dv;
    float c2 = coords[3 * v + 2] * dv;
    int t = at[v];
    float e0 = emb[3 * t + 0] * dv;
    float e1 = emb[3 * t + 1] * dv;
    float e2 = emb[3 * t + 2] * dv;
    uint* row = x + (size_t)v * 4;
    row[0] = f2_to_h2(c0, c1);
    row[1] = f2_to_h2(c2, e0);
    row[2] = f2_to_h2(e1, e2);
    row[3] = 0;
}

// ---------------- packed-half aggregation (R6 verbatim: unroll-4, plain loads, no NT) ----------
template <int FPH2, bool HAS_BIAS, bool RELU>
__global__ __launch_bounds__(256) void agg_h_kernel(const uint* __restrict__ in,
                                                    const float* __restrict__ dinv,
                                                    const int* __restrict__ rowptr,
                                                    const int* __restrict__ cnt,
                                                    const int* __restrict__ srcs,
                                                    const float* __restrict__ bias,
                                                    uint* __restrict__ out, int n) {
    int gid = blockIdx.x * 256 + threadIdx.x;
    int v = gid / FPH2, j2 = gid % FPH2;
    if (v >= n) return;
    float2 s0 = h2_to_f2(in[(size_t)v * FPH2 + j2]);
    float accx = s0.x, accy = s0.y;
    int start = rowptr[v];
    int len = cnt[v];
    int k = 0;
    for (; k + 4 <= len; k += 4) {
        int sA = srcs[start + k];
        int sB = srcs[start + k + 1];
        int sC = srcs[start + k + 2];
        int sD = srcs[start + k + 3];
        float2 fA = h2_to_f2(in[(size_t)sA * FPH2 + j2]);
        float2 fB = h2_to_f2(in[(size_t)sB * FPH2 + j2]);
        float2 fC = h2_to_f2(in[(size_t)sC * FPH2 + j2]);
        float2 fD = h2_to_f2(in[(size_t)sD * FPH2 + j2]);
        accx += (fA.x + fB.x) + (fC.x + fD.x);
        accy += (fA.y + fB.y) + (fC.y + fD.y);
    }
    for (; k < len; ++k) {
        int s = srcs[start + k];
        float2 f = h2_to_f2(in[(size_t)s * FPH2 + j2]);
        accx += f.x; accy += f.y;
    }
    float dv = dinv[v];
    accx *= dv; accy *= dv;
    if (HAS_BIAS) { accx += bias[2 * j2]; accy += bias[2 * j2 + 1]; }
    if (RELU) { accx = fmaxf(accx, 0.0f); accy = fmaxf(accy, 0.0f); }
    out[(size_t)v * FPH2 + j2] = f2_to_h2(accx, accy);
}

// ---------------- fused L4 agg + L5 gemm ----------------
// Gather loop byte-identical to agg_h<16,true,true>; epilogue computes the
// 3-wide W5 product via width-16 shfl_xor reduce and writes B_f directly.
// The 32-wide L4 output is never materialized (saves 12.8MB round trip + launch).
__global__ __launch_bounds__(256) void agg_l4l5_kernel(const uint* __restrict__ in,
                                                       const float* __restrict__ dinv,
                                                       const int* __restrict__ rowptr,
                                                       const int* __restrict__ cnt,
                                                       const int* __restrict__ srcs,
                                                       const float* __restrict__ b4,
                                                       const float* __restrict__ W5,
                                                       float* __restrict__ outf, int n) {
    int gid = blockIdx.x * 256 + threadIdx.x;
    int v = gid / 16, j2 = gid % 16;
    if (v >= n) return;   // grid exact (n*16 % 256 == 0): never splits a 16-lane group
    float2 s0 = h2_to_f2(in[(size_t)v * 16 + j2]);
    float accx = s0.x, accy = s0.y;
    int start = rowptr[v];
    int len = cnt[v];
    int k = 0;
    for (; k + 4 <= len; k += 4) {
        int sA = srcs[start + k];
        int sB = srcs[start + k + 1];
        int sC = srcs[start + k + 2];
        int sD = srcs[start + k + 3];
        float2 fA = h2_to_f2(in[(size_t)sA * 16 + j2]);
        float2 fB = h2_to_f2(in[(size_t)sB * 16 + j2]);
        float2 fC = h2_to_f2(in[(size_t)sC * 16 + j2]);
        float2 fD = h2_to_f2(in[(size_t)sD * 16 + j2]);
        accx += (fA.x + fB.x) + (fC.x + fD.x);
        accy += (fA.y + fB.y) + (fC.y + fD.y);
    }
    for (; k < len; ++k) {
        int s = srcs[start + k];
        float2 f = h2_to_f2(in[(size_t)s * 16 + j2]);
        accx += f.x; accy += f.y;
    }
    float dv = dinv[v];
    accx *= dv; accy *= dv;
    accx += b4[2 * j2]; accy += b4[2 * j2 + 1];
    accx = fmaxf(accx, 0.0f); accy = fmaxf(accy, 0.0f);
    // fused L5: p_c = sum_j feat[j] * W5[j][c]  (W5 is 32x3 row-major, L2-hot)
    int j1 = 2 * j2;
    float p0 = accx * W5[j1 * 3 + 0] + accy * W5[(j1 + 1) * 3 + 0];
    float p1 = accx * W5[j1 * 3 + 1] + accy * W5[(j1 + 1) * 3 + 1];
    float p2 = accx * W5[j1 * 3 + 2] + accy * W5[(j1 + 1) * 3 + 2];
#pragma unroll
    for (int m = 1; m < 16; m <<= 1) {
        p0 += __shfl_xor(p0, m, 16);
        p1 += __shfl_xor(p1, m, 16);
        p2 += __shfl_xor(p2, m, 16);
    }
    if (j2 < 3) {
        float o = (j2 == 0) ? p0 : (j2 == 1 ? p1 : p2);
        outf[(size_t)v * 4 + j2] = o * dv;   // dinv pre-scale for final agg (L5 SCALE)
    }
}

// ---------------- half GEMM: fp32 accumulate, packed-half out (plain loads) ----------------
template <int DIN, int DOUT, int DOUTH2, bool HAS_BIAS, bool RELU, bool SCALE>
__global__ __launch_bounds__(256) void gemm_h_kernel(const uint* __restrict__ xin,
                                                     const float* __restrict__ W,
                                                     const float* __restrict__ bias,
                                                     const float* __restrict__ dinv,
                                                     uint* __restrict__ xout,
                                                     int istride_u, int ostride, int n) {
    __shared__ float wlds[DIN * DOUT];
    for (int i = threadIdx.x; i < DIN * DOUT; i += 256) wlds[i] = W[i];
    __syncthreads();
    int gid = blockIdx.x * 256 + threadIdx.x;
    int v = gid / DOUTH2, j2 = gid % DOUTH2;
    if (v >= n) return;
    int j1 = 2 * j2;
    const uint* xr = xin + (size_t)v * istride_u;
    float acc0 = 0.0f, acc1 = 0.0f;
#pragma unroll
    for (int ku = 0; ku < DIN / 2; ++ku) {
        float2 xf = h2_to_f2(xr[ku]);
        int k = 2 * ku;
        acc0 = fmaf(xf.x, wlds[k * DOUT + j1], acc0);
        acc0 = fmaf(xf.y, wlds[(k + 1) * DOUT + j1], acc0);
        if (j1 + 1 < DOUT) {
            acc1 = fmaf(xf.x, wlds[k * DOUT + j1 + 1], acc1);
            acc1 = fmaf(xf.y, wlds[(k + 1) * DOUT + j1 + 1], acc1);
        }
    }
    if (HAS_BIAS) {
        acc0 += bias[j1];
        if (j1 + 1 < DOUT) acc1 += bias[j1 + 1];
    }
    if (RELU) { acc0 = fmaxf(acc0, 0.0f); acc1 = fmaxf(acc1, 0.0f); }
    if (SCALE) { float dv = dinv[v]; acc0 *= dv; acc1 *= dv; }
    xout[(size_t)v * ostride + j2] = f2_to_h2(acc0, acc1);
}

// ---------------- fused L3 gemm + L4 gemm ----------------
// y = (relu(x @ W3 + b3) @ W4) * dinv. 16 nodes/block, h staged fp32 in padded
// LDS (never quantized to half). Eliminates the 64-wide A_h round trip.
#define G34_NODES 16
__global__ __launch_bounds__(256) void gemm34_kernel(const uint* __restrict__ xin,   // stride 32 uints
                                                     const float* __restrict__ W3,  // 64x64
                                                     const float* __restrict__ b3,
                                                     const float* __restrict__ W4,  // 64x32
                                                     const float* __restrict__ dinv,
                                                     uint* __restrict__ xout,       // stride 16 uints
                                                     int n) {
    __shared__ float w3[64 * 64];
    __shared__ float w4[64 * 32];
    __shared__ float hb[G34_NODES][65];   // +1 pad: phase-2 broadcast across 4 node-groups
    for (int i = threadIdx.x; i < 64 * 64; i += 256) w3[i] = W3[i];
    for (int i = threadIdx.x; i < 64 * 32; i += 256) w4[i] = W4[i];
    __syncthreads();
    int i  = threadIdx.x >> 4;     // local node 0..15
    int j2 = threadIdx.x & 15;
    int v  = blockIdx.x * G34_NODES + i;
    bool ok = (v < n);
    int j1 = 2 * j2;
    // phase 1: h[j1], h[j1+1], h[j1+32], h[j1+33] = relu(x @ W3 + b3)
    float a0 = 0.f, a1 = 0.f, a2 = 0.f, a3 = 0.f;
    if (ok) {
        const uint* xr = xin + (size_t)v * 32;
#pragma unroll
        for (int ku = 0; ku < 32; ++ku) {
            float2 xf = h2_to_f2(xr[ku]);
            int k = 2 * ku;
            a0 = fmaf(xf.x, w3[k * 64 + j1],      a0);
            a0 = fmaf(xf.y, w3[(k + 1) * 64 + j1],      a0);
            a1 = fmaf(xf.x, w3[k * 64 + j1 + 1],  a1);
            a1 = fmaf(xf.y, w3[(k + 1) * 64 + j1 + 1],  a1);
            a2 = fmaf(xf.x, w3[k * 64 + j1 + 32], a2);
            a2 = fmaf(xf.y, w3[(k + 1) * 64 + j1 + 32], a2);
            a3 = fmaf(xf.x, w3[k * 64 + j1 + 33], a3);
            a3 = fmaf(xf.y, w3[(k + 1) * 64 + j1 + 33], a3);
        }
        hb[i][j1]      = fmaxf(a0 + b3[j1],      0.f);
        hb[i][j1 + 1]  = fmaxf(a1 + b3[j1 + 1],  0.f);
        hb[i][j1 + 32] = fmaxf(a2 + b3[j1 + 32], 0.f);
        hb[i][j1 + 33] = fmaxf(a3 + b3[j1 + 33], 0.f);
    }
    __syncthreads();
    // phase 2: y[j1], y[j1+1] = (h @ W4) * dinv
    float c0 = 0.f, c1 = 0.f;
#pragma unroll
    for (int k = 0; k < 64; ++k) {
        float hk = hb[i][k];
        c0 = fmaf(hk, w4[k * 32 + j1],     c0);
        c1 = fmaf(hk, w4[k * 32 + j1 + 1], c1);
    }
    if (ok) {
        float dv = dinv[v];
        xout[(size_t)v * 16 + j2] = f2_to_h2(c0 * dv, c1 * dv);
    }
}

// ---------------- fp32 final aggregation (L5; R6 verbatim, plain loads) ----------------
template <int F, int FP, bool HAS_BIAS, bool RELU>
__global__ __launch_bounds__(256) void agg_f_kernel(const float* __restrict__ in,
                                                    const float* __restrict__ dinv,
                                                    const int* __restrict__ rowptr,
                                                    const int* __restrict__ cnt,
                                                    const int* __restrict__ srcs,
                                                    const float* __restrict__ b,
                                                    float* __restrict__ out,
                                                    int istride, int ostride, int n) {
    int gid = blockIdx.x * 256 + threadIdx.x;
    int v = gid / FP, j = gid % FP;
    if (v >= n || j >= F) return;
    float dv = dinv[v];
    int start = rowptr[v];
    int len = cnt[v];
    float acc = in[(size_t)v * istride + j];
    int k = 0;
    for (; k + 4 <= len; k += 4) {
        int s0 = srcs[start + k];
        int s1 = srcs[start + k + 1];
        int s2 = srcs[start + k + 2];
        int s3 = srcs[start + k + 3];
        float a0 = in[(size_t)s0 * istride + j];
        float a1 = in[(size_t)s1 * istride + j];
        float a2 = in[(size_t)s2 * istride + j];
        float a3 = in[(size_t)s3 * istride + j];
        acc += (a0 + a1) + (a2 + a3);
    }
    for (; k < len; ++k) acc += in[(size_t)srcs[start + k] * istride + j];
    float val = acc * dv;
    if (HAS_BIAS) val += b[j];
    if (RELU) val = fmaxf(val, 0.0f);
    out[(size_t)v * ostride + j] = val;
}

// ---------------- driver ----------------

extern "C" void kernel_launch(void* const* d_in, const int* in_sizes, int n_in,
                              void* d_out, int out_size, void* d_ws, size_t ws_size,
                              hipStream_t stream) {
    const float* coords = (const float*)d_in[0];
    const int* at       = (const int*)d_in[1];
    const int* ei       = (const int*)d_in[2];
    const float* emb    = (const float*)d_in[3];
    const float* W1 = (const float*)d_in[4];  const float* b1 = (const float*)d_in[5];
    const float* W2 = (const float*)d_in[6];  const float* b2 = (const float*)d_in[7];
    const float* W3 = (const float*)d_in[8];  const float* b3 = (const float*)d_in[9];
    const float* W4 = (const float*)d_in[10]; const float* b4 = (const float*)d_in[11];
    const float* W5 = (const float*)d_in[12]; const float* b5 = (const float*)d_in[13];
    float* out = (float*)d_out;

    const int n = in_sizes[0] / 3;   // 100000
    const int e = in_sizes[2] / 2;   // 3200000
    const int* src = ei;
    const int* dst = ei + e;

    // workspace layout (pairs dies before feature buffers are born -> alias)
    char* ws = (char*)d_ws;
    size_t off = 0;
    float* dinv   = (float*)(ws + off); off += (size_t)n * 4;
    int*   cnt    = (int*)(ws + off);   off += (size_t)n * 4;
    int*   rowptr = (int*)(ws + off);   off += (size_t)n * 4;
    int*   blkcnt = (int*)(ws + off);   off += (size_t)NBLK_BIN * NBKT * 4;
    int*   srcs   = (int*)(ws + off);   off += (size_t)e * 4;
    char*  alias  = ws + off;           // max(pairs 51.4MB, A_h+B_h+B_f 27.2MB)
    int2*  pairs  = (int2*)alias;
    uint*  A_h    = (uint*)alias;                    // n x 32 uints
    uint*  B_h    = A_h + (size_t)n * 32;            // n x 32 uints
    float* B_f    = (float*)(B_h + (size_t)n * 32);  // n x 4 floats

    int nb = (n + 255) / 256;   // 391

    // ---- CSR build (R6 output structure; fill 1024-thr with in-block base) ----
    bin_kernel<<<NBLK_BIN, 1024, 0, stream>>>(src, dst, pairs, blkcnt, e);
    fill_kernel<<<NBKT, 1024, 0, stream>>>(pairs, blkcnt, srcs, cnt, rowptr, dinv, n);

    // ---- x0 (pre-scaled by dinv), half stride 4 uints, in A_h ----
    build_x0_h_kernel<<<nb, 256, 0, stream>>>(coords, at, emb, dinv, A_h, n);

    auto blocks = [](long long threads) { return (int)((threads + 255) / 256); };

    // L1: 6->32. agg width6(FPH2=4); gemm + bias + relu + dinv-prescale
    agg_h_kernel<4, false, false><<<blocks((long long)n * 4), 256, 0, stream>>>(
        A_h, dinv, rowptr, cnt, srcs, nullptr, B_h, n);
    gemm_h_kernel<6, 32, 16, true, true, true><<<blocks((long long)n * 16), 256, 0, stream>>>(
        B_h, W1, b1, dinv, A_h, 4, 16, n);

    // L2: 32->64. agg width32(FPH2=16); gemm + bias + relu + dinv-prescale
    agg_h_kernel<16, false, false><<<blocks((long long)n * 16), 256, 0, stream>>>(
        A_h, dinv, rowptr, cnt, srcs, nullptr, B_h, n);
    gemm_h_kernel<32, 64, 32, true, true, true><<<blocks((long long)n * 32), 256, 0, stream>>>(
        B_h, W2, b2, dinv, A_h, 16, 32, n);

    // L3: 64->64 agg; then fused (relu(xW3+b3) @ W4) * dinv -> A_h stride 16
    agg_h_kernel<32, false, false><<<blocks((long long)n * 32), 256, 0, stream>>>(
        A_h, dinv, rowptr, cnt, srcs, nullptr, B_h, n);
    gemm34_kernel<<<(n + G34_NODES - 1) / G34_NODES, 256, 0, stream>>>(
        B_h, W3, b3, W4, dinv, A_h, n);

    // L4+L5 fused: agg width32 + b4 + relu, then xW5*dinv via shfl reduce -> B_f
    agg_l4l5_kernel<<<blocks((long long)n * 16), 256, 0, stream>>>(
        A_h, dinv, rowptr, cnt, srcs, b4, W5, B_f, n);

    // final: agg over B_f + b5 -> out
    agg_f_kernel<3, 4, true, false><<<blocks((long long)n * 4), 256, 0, stream>>>(
        B_f, dinv, rowptr, cnt, srcs, b5, out, 4, 3, n);
}

// Round 4
// 426.126 us; speedup vs baseline: 1.2515x; 1.0106x over previous
//
#include <hip/hip_runtime.h>
#include <hip/hip_fp16.h>

// ---- R6 CSR-build constants (verbatim; load-bearing for agg locality) ----
#define NBLK_BIN 256   // bin blocks; chunking identical to r3/r5/r6 -> same per-cell counts
#define NBKT 196       // ceil(100000/512) dst-buckets
#define BWIN 512       // nodes per bucket
#define CAP 128        // slots per (block,bucket); lambda=63.8, +8 sigma -> no overflow

// NOTE (R8/R9 post-mortem): R6's exact CSR build (NBLK=256, CAP=128, monotone
// bucket bases, this fill structure) is empirically tied to the fast agg.
// R7-style atomic-span fill or finer bin chunking pushed agg FETCH +140MB.
// Keep CSR output structure EXACT; only change execution parallelism.
//
// NOTE (R10 post-mortem): __builtin_nontemporal on srcs reads / gemm input rows
// REGRESSED +80us (those accesses have heavy L1 reuse). No NT anywhere.
//
// R11 (WIN, -22us): L3gemm+L4gemm fused (gemm34, h fp32 in LDS); L5 gemm folded
// into L4 agg epilogue. Dense glue only; aggs byte-identical.
//
// R12: aggs were latency-bound at ~8 lines-in-flight per wave (32 thr/node x
// 4B loads, unroll-4). Rewritten as uint4 gathers (16B/lane, 8/4/1 thr/node):
// 4x lines-in-flight per wave, 4x less srcs redundancy, same CSR, same
// k-order per-feature summation (agg numerics bit-identical). Discriminating
// test: null result => per-CU MSHR cap => pivot to footprint reduction.
// (R3 bench attempt hit GPUAcquisitionTimeout — this is an unmodified resubmit.)

typedef unsigned int uint;

union U32H2 { uint u; __half2 h; };

__device__ inline float2 h2_to_f2(uint u) {
    U32H2 c; c.u = u;
    return __half22float2(c.h);
}
__device__ inline uint f2_to_h2(float a, float b) {
    U32H2 c; c.h = __floats2half2_rn(a, b);
    return c.u;
}

// ---------------- CSR build: bin pass (R6 verbatim: 1024 thr, no global atomics) ----------------
__global__ __launch_bounds__(1024) void bin_kernel(const int* __restrict__ src,
                                                   const int* __restrict__ dst,
                                                   int2* __restrict__ pairs,
                                                   int* __restrict__ blkcnt, int e) {
    __shared__ int lcnt[NBKT];
    int blk = blockIdx.x, tid = threadIdx.x;
    for (int t = tid; t < NBKT; t += 1024) lcnt[t] = 0;
    __syncthreads();
    int chunk = (e + NBLK_BIN - 1) / NBLK_BIN;
    int base = blk * chunk;
    int end = min(e, base + chunk);
    for (int i = base + tid; i < end; i += 1024) {
        int s = src[i], d = dst[i];
        int b = d >> 9;
        int pos = atomicAdd(&lcnt[b], 1);
        if (pos < CAP) pairs[((size_t)blk * NBKT + b) * CAP + pos] = make_int2(s, d);
    }
    __syncthreads();
    for (int t = tid; t < NBKT; t += 1024) blkcnt[blk * NBKT + t] = min(lcnt[t], CAP);
}

// ---------------- fused fill: in-block bucket base + counts + scan + cnt/rowptr/dinv + srcs ----
__global__ __launch_bounds__(1024) void fill_kernel(const int2* __restrict__ pairs,
                                                    const int* __restrict__ blkcnt,
                                                    int* __restrict__ srcs,
                                                    int* __restrict__ cnt,
                                                    int* __restrict__ rowptr,
                                                    float* __restrict__ dinv, int n) {
    __shared__ int lc[BWIN];
    __shared__ int ps[BWIN];
    __shared__ int sm[NBLK_BIN];
    __shared__ int gbase_s;
    int b = blockIdx.x, tid = threadIdx.x;
    int nbase = b << 9;
    if (tid < BWIN) lc[tid] = 0;
    for (int t = tid; t < NBLK_BIN; t += 1024) sm[t] = blkcnt[t * NBKT + b];
    if (tid == 0) gbase_s = 0;
    __syncthreads();
    // bucket base: sum over all bin-blocks of all buckets b' < b (L2-hot 200KB array)
    {
        long long tot = (long long)NBLK_BIN * b;
        int lsum = 0;
        for (long long j = tid; j < tot; j += 1024) {
            int blk = (int)(j / b);
            int bp  = (int)(j - (long long)blk * b);
            lsum += blkcnt[blk * NBKT + bp];
        }
        for (int o = 32; o > 0; o >>= 1) lsum += __shfl_down(lsum, o, 64);
        if ((tid & 63) == 0 && lsum != 0) atomicAdd(&gbase_s, lsum);
    }
    int wave = tid >> 6, lane = tid & 63;
    // pass 1: per-node counts (16 waves over 256 cells)
    for (int blk = wave; blk < NBLK_BIN; blk += 16) {
        int m = sm[blk];
        const int2* p = pairs + ((size_t)blk * NBKT + b) * CAP;
        for (int i = lane; i < m; i += 64) atomicAdd(&lc[p[i].y - nbase], 1);
    }
    __syncthreads();
    // exclusive scan of 512 counts
    int myc = (tid < BWIN) ? lc[tid] : 0;
    if (tid < BWIN) ps[tid] = myc;
    __syncthreads();
    for (int off = 1; off < BWIN; off <<= 1) {
        int t = 0;
        if (tid < BWIN && tid >= off) t = ps[tid - off];
        __syncthreads();
        if (tid < BWIN) ps[tid] += t;
        __syncthreads();
    }
    int gbase = gbase_s;
    if (tid < BWIN) {
        int ex = ps[tid] - myc;
        int vtx = nbase + tid;
        if (vtx < n) {
            cnt[vtx] = myc;
            rowptr[vtx] = gbase + ex;
            dinv[vtx] = rsqrtf(1.0f + (float)myc);   // +1: self-loop
        }
    }
    __syncthreads();
    if (tid < BWIN) lc[tid] = ps[tid] - myc;   // reuse as bucket-relative cursor
    __syncthreads();
    // pass 2: place srcs (contiguous monotone span for this bucket)
    for (int blk = wave; blk < NBLK_BIN; blk += 16) {
        int m = sm[blk];
        const int2* p = pairs + ((size_t)blk * NBKT + b) * CAP;
        for (int i = lane; i < m; i += 64) {
            int2 e2 = p[i];
            int o = atomicAdd(&lc[e2.y - nbase], 1);
            srcs[gbase + o] = e2.x;
        }
    }
}

// ---------------- input feature build: half, stride 4 uints, pre-scaled by dinv ----------------

__global__ __launch_bounds__(256) void build_x0_h_kernel(const float* __restrict__ coords,
                                                         const int* __restrict__ at,
                                                         const float* __restrict__ emb,
                                                         const float* __restrict__ dinv,
                                                         uint* __restrict__ x, int n) {
    int v = blockIdx.x * 256 + threadIdx.x;
    if (v >= n) return;
    float dv = dinv[v];
    float c0 = coords[3 * v + 0] * dv;
    float c1 = coords[3 * v + 1] * dv;
    float c2 = coords[3 * v + 2] * dv;
    int t = at[v];
    float e0 = emb[3 * t + 0] * dv;
    float e1 = emb[3 * t + 1] * dv;
    float e2 = emb[3 * t + 2] * dv;
    uint* row = x + (size_t)v * 4;
    row[0] = f2_to_h2(c0, c1);
    row[1] = f2_to_h2(c2, e0);
    row[2] = f2_to_h2(e1, e2);
    row[3] = 0;
}

// ---------------- R12 vectorized packed-half aggregation ----------------
// TPN = uint4s per row = threads per node. Each thread gathers one uint4
// (16B, 8 half features) per source. Unroll-4 over sources (R6 sweet spot).
// Per-feature accumulation order identical to the scalar agg (bit-identical).
template <int TPN, bool HAS_BIAS, bool RELU>
__global__ __launch_bounds__(256) void agg_v4_kernel(const uint* __restrict__ in_,
                                                     const float* __restrict__ dinv,
                                                     const int* __restrict__ rowptr,
                                                     const int* __restrict__ cnt,
                                                     const int* __restrict__ srcs,
                                                     const float* __restrict__ bias,
                                                     uint* __restrict__ out_, int n) {
    const uint4* in = (const uint4*)in_;
    uint4* out = (uint4*)out_;
    int gid = blockIdx.x * 256 + threadIdx.x;
    int v = gid / TPN, q = gid % TPN;
    if (v >= n) return;
    float ax[4], ay[4];
    {
        uint4 s0 = in[(size_t)v * TPN + q];
        uint su[4] = {s0.x, s0.y, s0.z, s0.w};
#pragma unroll
        for (int u = 0; u < 4; ++u) { float2 f = h2_to_f2(su[u]); ax[u] = f.x; ay[u] = f.y; }
    }
    int start = rowptr[v];
    int len = cnt[v];
    int k = 0;
    for (; k + 4 <= len; k += 4) {
        int sA = srcs[start + k];
        int sB = srcs[start + k + 1];
        int sC = srcs[start + k + 2];
        int sD = srcs[start + k + 3];
        uint4 fA = in[(size_t)sA * TPN + q];
        uint4 fB = in[(size_t)sB * TPN + q];
        uint4 fC = in[(size_t)sC * TPN + q];
        uint4 fD = in[(size_t)sD * TPN + q];
        uint ua[4] = {fA.x, fA.y, fA.z, fA.w};
        uint ub[4] = {fB.x, fB.y, fB.z, fB.w};
        uint uc[4] = {fC.x, fC.y, fC.z, fC.w};
        uint ud[4] = {fD.x, fD.y, fD.z, fD.w};
#pragma unroll
        for (int u = 0; u < 4; ++u) {
            float2 a = h2_to_f2(ua[u]);
            float2 b = h2_to_f2(ub[u]);
            float2 c = h2_to_f2(uc[u]);
            float2 d = h2_to_f2(ud[u]);
            ax[u] += (a.x + b.x) + (c.x + d.x);
            ay[u] += (a.y + b.y) + (c.y + d.y);
        }
    }
    for (; k < len; ++k) {
        int s = srcs[start + k];
        uint4 f = in[(size_t)s * TPN + q];
        uint uu[4] = {f.x, f.y, f.z, f.w};
#pragma unroll
        for (int u = 0; u < 4; ++u) { float2 t = h2_to_f2(uu[u]); ax[u] += t.x; ay[u] += t.y; }
    }
    float dv = dinv[v];
#pragma unroll
    for (int u = 0; u < 4; ++u) {
        ax[u] *= dv; ay[u] *= dv;
        if (HAS_BIAS) { ax[u] += bias[8 * q + 2 * u]; ay[u] += bias[8 * q + 2 * u + 1]; }
        if (RELU) { ax[u] = fmaxf(ax[u], 0.0f); ay[u] = fmaxf(ay[u], 0.0f); }
    }
    uint4 o;
    o.x = f2_to_h2(ax[0], ay[0]);
    o.y = f2_to_h2(ax[1], ay[1]);
    o.z = f2_to_h2(ax[2], ay[2]);
    o.w = f2_to_h2(ax[3], ay[3]);
    out[(size_t)v * TPN + q] = o;
}

// ---------------- fused L4 agg + L5 gemm (R12: TPN=4 uint4 gathers) ----------------
// Gather identical to agg_v4<4,...>; epilogue: per-thread 8-feature W5 partial,
// width-4 shfl_xor reduce, lanes q<3 write p_c*dinv (L5 prescale), q==3 writes 0.
__global__ __launch_bounds__(256) void agg_l4l5_kernel(const uint* __restrict__ in_,
                                                       const float* __restrict__ dinv,
                                                       const int* __restrict__ rowptr,
                                                       const int* __restrict__ cnt,
                                                       const int* __restrict__ srcs,
                                                       const float* __restrict__ b4,
                                                       const float* __restrict__ W5,
                                                       float* __restrict__ outf, int n) {
    const uint4* in = (const uint4*)in_;
    int gid = blockIdx.x * 256 + threadIdx.x;
    int v = gid >> 2, q = gid & 3;
    if (v >= n) return;   // 4 | 256: node groups never split, shfl-safe
    float ax[4], ay[4];
    {
        uint4 s0 = in[(size_t)v * 4 + q];
        uint su[4] = {s0.x, s0.y, s0.z, s0.w};
#pragma unroll
        for (int u = 0; u < 4; ++u) { float2 f = h2_to_f2(su[u]); ax[u] = f.x; ay[u] = f.y; }
    }
    int start = rowptr[v];
    int len = cnt[v];
    int k = 0;
    for (; k + 4 <= len; k += 4) {
        int sA = srcs[start + k];
        int sB = srcs[start + k + 1];
        int sC = srcs[start + k + 2];
        int sD = srcs[start + k + 3];
        uint4 fA = in[(size_t)sA * 4 + q];
        uint4 fB = in[(size_t)sB * 4 + q];
        uint4 fC = in[(size_t)sC * 4 + q];
        uint4 fD = in[(size_t)sD * 4 + q];
        uint ua[4] = {fA.x, fA.y, fA.z, fA.w};
        uint ub[4] = {fB.x, fB.y, fB.z, fB.w};
        uint uc[4] = {fC.x, fC.y, fC.z, fC.w};
        uint ud[4] = {fD.x, fD.y, fD.z, fD.w};
#pragma unroll
        for (int u = 0; u < 4; ++u) {
            float2 a = h2_to_f2(ua[u]);
            float2 b = h2_to_f2(ub[u]);
            float2 c = h2_to_f2(uc[u]);
            float2 d = h2_to_f2(ud[u]);
            ax[u] += (a.x + b.x) + (c.x + d.x);
            ay[u] += (a.y + b.y) + (c.y + d.y);
        }
    }
    for (; k < len; ++k) {
        int s = srcs[start + k];
        uint4 f = in[(size_t)s * 4 + q];
        uint uu[4] = {f.x, f.y, f.z, f.w};
#pragma unroll
        for (int u = 0; u < 4; ++u) { float2 t = h2_to_f2(uu[u]); ax[u] += t.x; ay[u] += t.y; }
    }
    float dv = dinv[v];
    float feat[8];
#pragma unroll
    for (int u = 0; u < 4; ++u) {
        float fx = ax[u] * dv + b4[8 * q + 2 * u];
        float fy = ay[u] * dv + b4[8 * q + 2 * u + 1];
        feat[2 * u]     = fmaxf(fx, 0.0f);
        feat[2 * u + 1] = fmaxf(fy, 0.0f);
    }
    // L5 partial: p_c = sum_{m} feat[m] * W5[(8q+m)*3 + c]  (W5 32x3, L2-hot)
    float p0 = 0.f, p1 = 0.f, p2 = 0.f;
#pragma unroll
    for (int m = 0; m < 8; ++m) {
        int j = 8 * q + m;
        p0 = fmaf(feat[m], W5[j * 3 + 0], p0);
        p1 = fmaf(feat[m], W5[j * 3 + 1], p1);
        p2 = fmaf(feat[m], W5[j * 3 + 2], p2);
    }
#pragma unroll
    for (int m = 1; m < 4; m <<= 1) {
        p0 += __shfl_xor(p0, m, 4);
        p1 += __shfl_xor(p1, m, 4);
        p2 += __shfl_xor(p2, m, 4);
    }
    float o = (q == 0) ? p0 : (q == 1 ? p1 : (q == 2 ? p2 : 0.0f));
    outf[(size_t)v * 4 + q] = (q < 3) ? o * dv : 0.0f;   // dinv prescale for final agg
}

// ---------------- half GEMM: fp32 accumulate, packed-half out (plain loads) ----------------
template <int DIN, int DOUT, int DOUTH2, bool HAS_BIAS, bool RELU, bool SCALE>
__global__ __launch_bounds__(256) void gemm_h_kernel(const uint* __restrict__ xin,
                                                     const float* __restrict__ W,
                                                     const float* __restrict__ bias,
                                                     const float* __restrict__ dinv,
                                                     uint* __restrict__ xout,
                                                     int istride_u, int ostride, int n) {
    __shared__ float wlds[DIN * DOUT];
    for (int i = threadIdx.x; i < DIN * DOUT; i += 256) wlds[i] = W[i];
    __syncthreads();
    int gid = blockIdx.x * 256 + threadIdx.x;
    int v = gid / DOUTH2, j2 = gid % DOUTH2;
    if (v >= n) return;
    int j1 = 2 * j2;
    const uint* xr = xin + (size_t)v * istride_u;
    float acc0 = 0.0f, acc1 = 0.0f;
#pragma unroll
    for (int ku = 0; ku < DIN / 2; ++ku) {
        float2 xf = h2_to_f2(xr[ku]);
        int k = 2 * ku;
        acc0 = fmaf(xf.x, wlds[k * DOUT + j1], acc0);
        acc0 = fmaf(xf.y, wlds[(k + 1) * DOUT + j1], acc0);
        if (j1 + 1 < DOUT) {
            acc1 = fmaf(xf.x, wlds[k * DOUT + j1 + 1], acc1);
            acc1 = fmaf(xf.y, wlds[(k + 1) * DOUT + j1 + 1], acc1);
        }
    }
    if (HAS_BIAS) {
        acc0 += bias[j1];
        if (j1 + 1 < DOUT) acc1 += bias[j1 + 1];
    }
    if (RELU) { acc0 = fmaxf(acc0, 0.0f); acc1 = fmaxf(acc1, 0.0f); }
    if (SCALE) { float dv = dinv[v]; acc0 *= dv; acc1 *= dv; }
    xout[(size_t)v * ostride + j2] = f2_to_h2(acc0, acc1);
}

// ---------------- fused L3 gemm + L4 gemm (R11 verbatim) ----------------
#define G34_NODES 16
__global__ __launch_bounds__(256) void gemm34_kernel(const uint* __restrict__ xin,   // stride 32 uints
                                                     const float* __restrict__ W3,  // 64x64
                                                     const float* __restrict__ b3,
                                                     const float* __restrict__ W4,  // 64x32
                                                     const float* __restrict__ dinv,
                                                     uint* __restrict__ xout,       // stride 16 uints
                                                     int n) {
    __shared__ float w3[64 * 64];
    __shared__ float w4[64 * 32];
    __shared__ float hb[G34_NODES][65];   // +1 pad
    for (int i = threadIdx.x; i < 64 * 64; i += 256) w3[i] = W3[i];
    for (int i = threadIdx.x; i < 64 * 32; i += 256) w4[i] = W4[i];
    __syncthreads();
    int i  = threadIdx.x >> 4;     // local node 0..15
    int j2 = threadIdx.x & 15;
    int v  = blockIdx.x * G34_NODES + i;
    bool ok = (v < n);
    int j1 = 2 * j2;
    float a0 = 0.f, a1 = 0.f, a2 = 0.f, a3 = 0.f;
    if (ok) {
        const uint* xr = xin + (size_t)v * 32;
#pragma unroll
        for (int ku = 0; ku < 32; ++ku) {
            float2 xf = h2_to_f2(xr[ku]);
            int k = 2 * ku;
            a0 = fmaf(xf.x, w3[k * 64 + j1],      a0);
            a0 = fmaf(xf.y, w3[(k + 1) * 64 + j1],      a0);
            a1 = fmaf(xf.x, w3[k * 64 + j1 + 1],  a1);
            a1 = fmaf(xf.y, w3[(k + 1) * 64 + j1 + 1],  a1);
            a2 = fmaf(xf.x, w3[k * 64 + j1 + 32], a2);
            a2 = fmaf(xf.y, w3[(k + 1) * 64 + j1 + 32], a2);
            a3 = fmaf(xf.x, w3[k * 64 + j1 + 33], a3);
            a3 = fmaf(xf.y, w3[(k + 1) * 64 + j1 + 33], a3);
        }
        hb[i][j1]      = fmaxf(a0 + b3[j1],      0.f);
        hb[i][j1 + 1]  = fmaxf(a1 + b3[j1 + 1],  0.f);
        hb[i][j1 + 32] = fmaxf(a2 + b3[j1 + 32], 0.f);
        hb[i][j1 + 33] = fmaxf(a3 + b3[j1 + 33], 0.f);
    }
    __syncthreads();
    float c0 = 0.f, c1 = 0.f;
#pragma unroll
    for (int k = 0; k < 64; ++k) {
        float hk = hb[i][k];
        c0 = fmaf(hk, w4[k * 32 + j1],     c0);
        c1 = fmaf(hk, w4[k * 32 + j1 + 1], c1);
    }
    if (ok) {
        float dv = dinv[v];
        xout[(size_t)v * 16 + j2] = f2_to_h2(c0 * dv, c1 * dv);
    }
}

// ---------------- fp32 final aggregation (R12: 1 thread/node, float4 gathers) ----------------
__global__ __launch_bounds__(256) void agg_f4_kernel(const float* __restrict__ in_,
                                                     const float* __restrict__ dinv,
                                                     const int* __restrict__ rowptr,
                                                     const int* __restrict__ cnt,
                                                     const int* __restrict__ srcs,
                                                     const float* __restrict__ b,
                                                     float* __restrict__ out, int n) {
    const float4* in = (const float4*)in_;
    int v = blockIdx.x * 256 + threadIdx.x;
    if (v >= n) return;
    float4 s = in[v];
    float a0 = s.x, a1 = s.y, a2 = s.z;   // elem 3 is zero-filled by agg_l4l5
    int start = rowptr[v];
    int len = cnt[v];
    int k = 0;
    for (; k + 4 <= len; k += 4) {
        int sA = srcs[start + k];
        int sB = srcs[start + k + 1];
        int sC = srcs[start + k + 2];
        int sD = srcs[start + k + 3];
        float4 fA = in[sA];
        float4 fB = in[sB];
        float4 fC = in[sC];
        float4 fD = in[sD];
        a0 += (fA.x + fB.x) + (fC.x + fD.x);
        a1 += (fA.y + fB.y) + (fC.y + fD.y);
        a2 += (fA.z + fB.z) + (fC.z + fD.z);
    }
    for (; k < len; ++k) {
        float4 f = in[srcs[start + k]];
        a0 += f.x; a1 += f.y; a2 += f.z;
    }
    float dv = dinv[v];
    out[(size_t)v * 3 + 0] = a0 * dv + b[0];
    out[(size_t)v * 3 + 1] = a1 * dv + b[1];
    out[(size_t)v * 3 + 2] = a2 * dv + b[2];
}

// ---------------- driver ----------------

extern "C" void kernel_launch(void* const* d_in, const int* in_sizes, int n_in,
                              void* d_out, int out_size, void* d_ws, size_t ws_size,
                              hipStream_t stream) {
    const float* coords = (const float*)d_in[0];
    const int* at       = (const int*)d_in[1];
    const int* ei       = (const int*)d_in[2];
    const float* emb    = (const float*)d_in[3];
    const float* W1 = (const float*)d_in[4];  const float* b1 = (const float*)d_in[5];
    const float* W2 = (const float*)d_in[6];  const float* b2 = (const float*)d_in[7];
    const float* W3 = (const float*)d_in[8];  const float* b3 = (const float*)d_in[9];
    const float* W4 = (const float*)d_in[10]; const float* b4 = (const float*)d_in[11];
    const float* W5 = (const float*)d_in[12]; const float* b5 = (const float*)d_in[13];
    float* out = (float*)d_out;

    const int n = in_sizes[0] / 3;   // 100000
    const int e = in_sizes[2] / 2;   // 3200000
    const int* src = ei;
    const int* dst = ei + e;

    // workspace layout (pairs dies before feature buffers are born -> alias)
    char* ws = (char*)d_ws;
    size_t off = 0;
    float* dinv   = (float*)(ws + off); off += (size_t)n * 4;
    int*   cnt    = (int*)(ws + off);   off += (size_t)n * 4;
    int*   rowptr = (int*)(ws + off);   off += (size_t)n * 4;
    int*   blkcnt = (int*)(ws + off);   off += (size_t)NBLK_BIN * NBKT * 4;
    int*   srcs   = (int*)(ws + off);   off += (size_t)e * 4;
    char*  alias  = ws + off;           // max(pairs 51.4MB, A_h+B_h+B_f 27.2MB); 16B aligned
    int2*  pairs  = (int2*)alias;
    uint*  A_h    = (uint*)alias;                    // n x 32 uints
    uint*  B_h    = A_h + (size_t)n * 32;            // n x 32 uints
    float* B_f    = (float*)(B_h + (size_t)n * 32);  // n x 4 floats

    int nb = (n + 255) / 256;   // 391

    // ---- CSR build (R6 output structure; fill 1024-thr with in-block base) ----
    bin_kernel<<<NBLK_BIN, 1024, 0, stream>>>(src, dst, pairs, blkcnt, e);
    fill_kernel<<<NBKT, 1024, 0, stream>>>(pairs, blkcnt, srcs, cnt, rowptr, dinv, n);

    // ---- x0 (pre-scaled by dinv), half stride 4 uints, in A_h ----
    build_x0_h_kernel<<<nb, 256, 0, stream>>>(coords, at, emb, dinv, A_h, n);

    auto blocks = [](long long threads) { return (int)((threads + 255) / 256); };

    // L1: 6->32. agg rows 16B (TPN=1); gemm + bias + relu + dinv-prescale
    agg_v4_kernel<1, false, false><<<blocks((long long)n), 256, 0, stream>>>(
        A_h, dinv, rowptr, cnt, srcs, nullptr, B_h, n);
    gemm_h_kernel<6, 32, 16, true, true, true><<<blocks((long long)n * 16), 256, 0, stream>>>(
        B_h, W1, b1, dinv, A_h, 4, 16, n);

    // L2: 32->64. agg rows 64B (TPN=4); gemm + bias + relu + dinv-prescale
    agg_v4_kernel<4, false, false><<<blocks((long long)n * 4), 256, 0, stream>>>(
        A_h, dinv, rowptr, cnt, srcs, nullptr, B_h, n);
    gemm_h_kernel<32, 64, 32, true, true, true><<<blocks((long long)n * 32), 256, 0, stream>>>(
        B_h, W2, b2, dinv, A_h, 16, 32, n);

    // L3: 64->64 agg rows 128B (TPN=8); then fused (relu(xW3+b3) @ W4) * dinv
    agg_v4_kernel<8, false, false><<<blocks((long long)n * 8), 256, 0, stream>>>(
        A_h, dinv, rowptr, cnt, srcs, nullptr, B_h, n);
    gemm34_kernel<<<(n + G34_NODES - 1) / G34_NODES, 256, 0, stream>>>(
        B_h, W3, b3, W4, dinv, A_h, n);

    // L4+L5 fused: agg rows 64B (TPN=4) + b4 + relu, then xW5*dinv -> B_f
    agg_l4l5_kernel<<<blocks((long long)n * 4), 256, 0, stream>>>(
        A_h, dinv, rowptr, cnt, srcs, b4, W5, B_f, n);

    // final: agg over B_f (float4, 1 thread/node) + b5 -> out
    agg_f4_kernel<<<blocks((long long)n), 256, 0, stream>>>(
        B_f, dinv, rowptr, cnt, srcs, b5, out, n);
}